// Round 3
// baseline (79.757 us; speedup 1.0000x reference)
//
#include <hip/hip_runtime.h>

namespace {

constexpr int H = 128, W = 128;
constexpr int NPIX = H * W;          // 16384 pixels, each a float4 over T=4
constexpr float GAMMA_W = 3.3257199f;
constexpr int NSL = 10;              // slices: 5 di x 2 dj-halves

__device__ __forceinline__ void load4(const float4* __restrict__ p, float o[4]) {
    const float4 v = *p;
    o[0] = v.x; o[1] = v.y; o[2] = v.z; o[3] = v.w;
}

// block = 64 pixels x 10 slices = 640 threads (10 waves, 1 block/CU)
__global__ __launch_bounds__(640) void statden(
    const float4* __restrict__ noisy,   // [3][NPIX]
    const float4* __restrict__ guid,    // [9][NPIX]
    const float4* __restrict__ est,     // [3][NPIX]
    const float4* __restrict__ var,     // [3][NPIX]
    float4* __restrict__ out)           // [3][NPIX]
{
    const float sig[9] = {0.1f, 0.1f, 0.1f, 50.f, 50.f, 50.f, 10.f, 10.f, 10.f};
    // t(w) <= gamma  <=>  w <= 1 - 1/(2*(gamma^2+1))
    const float WMAX = (float)(1.0 - 1.0 / (2.0 * ((double)GAMMA_W * (double)GAMMA_W + 1.0)));

    const int tid = threadIdx.x;
    const int p   = tid & 63;           // pixel lane
    const int s   = tid >> 6;           // slice 0..9
    const int pid = blockIdx.x * 64 + p;
    const int h   = pid >> 7;
    const int w   = pid & 127;
    const bool halfA = (s < 5);
    const int di    = (halfA ? s : s - 5) - 2;

    // ---- center (hoisted): sig*gc, qc = sum sig*gc^2, est/var centers ----
    float sgc[9][4], qc[4] = {0.f, 0.f, 0.f, 0.f};
    float ecv[3][4], vcv[3][4];
    {
        float g[4];
#pragma unroll
        for (int c = 0; c < 9; ++c) {
            load4(guid + c * NPIX + pid, g);
#pragma unroll
            for (int t = 0; t < 4; ++t) {
                sgc[c][t] = sig[c] * g[t];
                qc[t] += sgc[c][t] * g[t];
            }
        }
#pragma unroll
        for (int c = 0; c < 3; ++c) {
            load4(est + c * NPIX + pid, ecv[c]);
            load4(var + c * NPIX + pid, vcv[c]);
        }
    }

    float acc[3][4] = {};
    float den[4] = {0.f, 0.f, 0.f, 0.f};

    const int hh = h + di;
    if ((unsigned)hh < (unsigned)H) {
        auto process = [&](int dj) {
            const int ww = w + dj;
            if ((unsigned)ww >= (unsigned)W) return;
            const int q = hh * W + ww;

            float gj[9][4], ej[3][4], vj[3][4], nj[3][4];
#pragma unroll
            for (int c = 0; c < 9; ++c) load4(guid + c * NPIX + q, gj[c]);
#pragma unroll
            for (int c = 0; c < 3; ++c) {
                load4(est   + c * NPIX + q, ej[c]);
                load4(var   + c * NPIX + q, vj[c]);
                load4(noisy + c * NPIX + q, nj[c]);
            }

#pragma unroll
            for (int tt = 0; tt < 4; ++tt) {
                float qj = 0.f;
#pragma unroll
                for (int c = 0; c < 9; ++c) qj += sig[c] * gj[c][tt] * gj[c][tt];
                float cross[4] = {0.f, 0.f, 0.f, 0.f};
#pragma unroll
                for (int c = 0; c < 9; ++c) {
                    const float gv = gj[c][tt];
#pragma unroll
                    for (int t = 0; t < 4; ++t) cross[t] += gv * sgc[c][t];
                }
#pragma unroll
                for (int t = 0; t < 4; ++t) {
                    if (tt - t > 2 || t - tt > 2) continue;   // |dk|>2: not a patch
                    const float sv = qj + qc[t] - 2.f * cross[t];
                    bool member = true;
#pragma unroll
                    for (int c = 0; c < 3; ++c) {
                        const float ejv = ej[c][tt], vjv = vj[c][tt];
                        const float d   = ecv[c][t] - ejv;
                        const float d2  = d * d;
                        const float S   = vcv[c][t] + vjv;
                        const float num = 2.f * d2 + S;
                        const float dn  = num + S;          // = 2*(d2 + vi + vj)
                        bool pass = (num <= WMAX * dn);     // den==0 -> 0<=0 pass (w=0.5)
                        if (((vcv[c][t] == 0.f) || (vjv == 0.f)) && (d != 0.f)) pass = false;
                        member = member && pass;
                    }
                    const float f = member ? __expf(-0.5f * sv) : 0.f;
                    den[t] += f;
#pragma unroll
                    for (int c = 0; c < 3; ++c) acc[c][t] += f * nj[c][tt];
                }
            }
        };
        if (halfA) { process(-2); process(-1); process(0); }
        else       { process(1);  process(2); }
    }

    // ---- reduce the 10 slices via LDS (inner dim padded to 17: odd bank stride) ----
    __shared__ float red[NSL][64][17];
    {
        float* r = &red[s][p][0];
#pragma unroll
        for (int c = 0; c < 3; ++c)
#pragma unroll
            for (int t = 0; t < 4; ++t) r[c * 4 + t] = acc[c][t];
#pragma unroll
        for (int t = 0; t < 4; ++t) r[12 + t] = den[t];
    }
    __syncthreads();

    if (tid < 64) {
#pragma unroll
        for (int k = 1; k < NSL; ++k) {
            const float* r2 = &red[k][p][0];
#pragma unroll
            for (int c = 0; c < 3; ++c)
#pragma unroll
                for (int t = 0; t < 4; ++t) acc[c][t] += r2[c * 4 + t];
#pragma unroll
            for (int t = 0; t < 4; ++t) den[t] += r2[12 + t];
        }

        // ---- OOB (zero-padded) patches: member iff all ec==0; bw = exp(-qc/2) ----
        const int nh  = min(h + 2, H - 1) - max(h - 2, 0) + 1;
        const int nw  = min(w + 2, W - 1) - max(w - 2, 0) + 1;
        const int nhw = nh * nw;
        const int ntt[4] = {3, 4, 4, 3};
#pragma unroll
        for (int t = 0; t < 4; ++t) {
            const int oob = 125 - nhw * ntt[t];
            const bool allz = (ecv[0][t] == 0.f) && (ecv[1][t] == 0.f) && (ecv[2][t] == 0.f);
            const float f = allz ? __expf(-0.5f * qc[t]) : 0.f;
            den[t] += (float)oob * f;
        }

        float ot[3][4];
#pragma unroll
        for (int t = 0; t < 4; ++t) {
            const float inv = 1.0f / fmaxf(den[t], 1e-12f);
#pragma unroll
            for (int c = 0; c < 3; ++c) ot[c][t] = acc[c][t] * inv;
        }
#pragma unroll
        for (int c = 0; c < 3; ++c) {
            float4 v;
            v.x = ot[c][0]; v.y = ot[c][1]; v.z = ot[c][2]; v.w = ot[c][3];
            out[c * NPIX + pid] = v;
        }
    }
}

} // namespace

extern "C" void kernel_launch(void* const* d_in, const int* in_sizes, int n_in,
                              void* d_out, int out_size, void* d_ws, size_t ws_size,
                              hipStream_t stream)
{
    const float4* noisy = (const float4*)d_in[0];
    const float4* guid  = (const float4*)d_in[1];
    const float4* est   = (const float4*)d_in[2];
    const float4* var   = (const float4*)d_in[3];
    float4* out = (float4*)d_out;

    statden<<<NPIX / 64, 640, 0, stream>>>(noisy, guid, est, var, out);
}

// Round 4
// 47.612 us; speedup vs baseline: 1.6751x; 1.6751x over previous
//
#include <hip/hip_runtime.h>

namespace {

constexpr int H = 128, W = 128;
constexpr int NPIX = H * W;          // 16384 pixels, each float4 over T=4
constexpr float GAMMA_W = 3.3257199f;
constexpr int PX = 16;               // pixels per block
constexpr int NSL = 20;              // slices: 5 di x 4 tt
constexpr int NTHR = PX * NSL;       // 320

__device__ __forceinline__ void load4(const float* __restrict__ p, float o[4]) {
    const float4 v = *reinterpret_cast<const float4*>(p);
    o[0] = v.x; o[1] = v.y; o[2] = v.z; o[3] = v.w;
}

// block = 16 pixels x 20 slices (5 di x 4 tt) = 320 threads.
// slice order s = di*4 + tt  ->  each wave = one di, all tt: uniform control flow.
__global__ __launch_bounds__(NTHR, 2) void statden(
    const float* __restrict__ noisy,   // [3][NPIX][4]
    const float* __restrict__ guid,    // [9][NPIX][4]
    const float* __restrict__ est,     // [3][NPIX][4]
    const float* __restrict__ var,     // [3][NPIX][4]
    float* __restrict__ out)           // [3][NPIX][4]
{
    const float sig[9] = {0.1f, 0.1f, 0.1f, 50.f, 50.f, 50.f, 10.f, 10.f, 10.f};
    // t(w) <= gamma  <=>  w <= 1 - 1/(2*(gamma^2+1))
    const float WMAX = (float)(1.0 - 1.0 / (2.0 * ((double)GAMMA_W * (double)GAMMA_W + 1.0)));

    const int tid = threadIdx.x;
    const int p   = tid & (PX - 1);     // pixel lane 0..15
    const int s   = tid >> 4;           // slice 0..19
    const int di  = (s >> 2) - 2;       // -2..2
    const int tt  = s & 3;              // source t 0..3
    const int pid = blockIdx.x * PX + p;
    const int h   = pid >> 7;
    const int w   = pid & 127;

    // ---- center (hoisted): sig*gc, qc = sum sig*gc^2, est/var centers ----
    float sgc[9][4], qc[4] = {0.f, 0.f, 0.f, 0.f};
    float ecv[3][4], vcv[3][4];
    {
        float g[4];
#pragma unroll
        for (int c = 0; c < 9; ++c) {
            load4(guid + (c * NPIX + pid) * 4, g);
#pragma unroll
            for (int t = 0; t < 4; ++t) {
                sgc[c][t] = sig[c] * g[t];
                qc[t] += sgc[c][t] * g[t];
            }
        }
#pragma unroll
        for (int c = 0; c < 3; ++c) {
            load4(est + (c * NPIX + pid) * 4, ecv[c]);
            load4(var + (c * NPIX + pid) * 4, vcv[c]);
        }
    }

    float acc[3][4] = {};
    float den[4] = {0.f, 0.f, 0.f, 0.f};

    const int hh = h + di;
    if ((unsigned)hh < (unsigned)H) {
#pragma unroll
        for (int dj = -2; dj <= 2; ++dj) {
            const int ww = w + dj;
            if ((unsigned)ww >= (unsigned)W) continue;
            const int q4 = (hh * W + ww) * 4 + tt;   // scalar index for this thread's tt

            // loads: only this thread's tt slot
            float gj[9], ej[3], vj[3], nj[3];
#pragma unroll
            for (int c = 0; c < 9; ++c) gj[c] = guid[c * NPIX * 4 + q4];
#pragma unroll
            for (int c = 0; c < 3; ++c) {
                ej[c] = est[c * NPIX * 4 + q4];
                vj[c] = var[c * NPIX * 4 + q4];
                nj[c] = noisy[c * NPIX * 4 + q4];
            }

            float qj = 0.f;
#pragma unroll
            for (int c = 0; c < 9; ++c) qj += sig[c] * gj[c] * gj[c];
            float cross[4] = {0.f, 0.f, 0.f, 0.f};
#pragma unroll
            for (int c = 0; c < 9; ++c) {
                const float gv = gj[c];
#pragma unroll
                for (int t = 0; t < 4; ++t) cross[t] += gv * sgc[c][t];
            }
#pragma unroll
            for (int t = 0; t < 4; ++t) {
                if (tt - t > 2 || t - tt > 2) continue;   // |dk|>2: not a patch (runtime tt ok)
                const float sv = qj + qc[t] - 2.f * cross[t];
                bool member = true;
#pragma unroll
                for (int c = 0; c < 3; ++c) {
                    const float d   = ecv[c][t] - ej[c];
                    const float d2  = d * d;
                    const float S   = vcv[c][t] + vj[c];
                    const float num = 2.f * d2 + S;
                    const float dn  = num + S;          // = 2*(d2 + vi + vj)
                    bool pass = (num <= WMAX * dn);     // den==0 -> 0<=0 pass (w=0.5)
                    if (((vcv[c][t] == 0.f) || (vj[c] == 0.f)) && (d != 0.f)) pass = false;
                    member = member && pass;
                }
                const float f = member ? __expf(-0.5f * sv) : 0.f;
                den[t] += f;
#pragma unroll
                for (int c = 0; c < 3; ++c) acc[c][t] += f * nj[c];
            }
        }
    }

    // ---- reduce 20 slices via LDS; inner stride 17 (coprime with 32 banks) ----
    __shared__ float red[NSL][PX][17];
    {
        float* r = &red[s][p][0];
#pragma unroll
        for (int c = 0; c < 3; ++c)
#pragma unroll
            for (int t = 0; t < 4; ++t) r[c * 4 + t] = acc[c][t];
#pragma unroll
        for (int t = 0; t < 4; ++t) r[12 + t] = den[t];
    }
    __syncthreads();

    // 20 -> 10
    if (tid < 10 * PX) {
        float* a = &red[s][p][0];
        const float* b = &red[s + 10][p][0];
#pragma unroll
        for (int i = 0; i < 16; ++i) a[i] += b[i];
    }
    __syncthreads();
    // 10 -> 5
    if (tid < 5 * PX) {
        float* a = &red[s][p][0];
        const float* b = &red[s + 5][p][0];
#pragma unroll
        for (int i = 0; i < 16; ++i) a[i] += b[i];
    }
    __syncthreads();

    if (tid < PX) {
        // s == 0 here, so this thread's ecv/qc are its own pixel's centers.
#pragma unroll
        for (int c = 0; c < 3; ++c)
#pragma unroll
            for (int t = 0; t < 4; ++t) acc[c][t] = red[0][p][c * 4 + t];
#pragma unroll
        for (int t = 0; t < 4; ++t) den[t] = red[0][p][12 + t];
#pragma unroll
        for (int k = 1; k < 5; ++k) {
            const float* r2 = &red[k][p][0];
#pragma unroll
            for (int c = 0; c < 3; ++c)
#pragma unroll
                for (int t = 0; t < 4; ++t) acc[c][t] += r2[c * 4 + t];
#pragma unroll
            for (int t = 0; t < 4; ++t) den[t] += r2[12 + t];
        }

        // ---- OOB (zero-padded) patches: member iff all ec==0; bw = exp(-qc/2) ----
        const int nh  = min(h + 2, H - 1) - max(h - 2, 0) + 1;
        const int nw  = min(w + 2, W - 1) - max(w - 2, 0) + 1;
        const int nhw = nh * nw;
        const int ntt[4] = {3, 4, 4, 3};
#pragma unroll
        for (int t = 0; t < 4; ++t) {
            const int oob = 125 - nhw * ntt[t];
            const bool allz = (ecv[0][t] == 0.f) && (ecv[1][t] == 0.f) && (ecv[2][t] == 0.f);
            const float f = allz ? __expf(-0.5f * qc[t]) : 0.f;
            den[t] += (float)oob * f;
        }

#pragma unroll
        for (int t = 0; t < 4; ++t) {
            const float inv = 1.0f / fmaxf(den[t], 1e-12f);
#pragma unroll
            for (int c = 0; c < 3; ++c) acc[c][t] *= inv;
        }
#pragma unroll
        for (int c = 0; c < 3; ++c) {
            float4 v;
            v.x = acc[c][0]; v.y = acc[c][1]; v.z = acc[c][2]; v.w = acc[c][3];
            *reinterpret_cast<float4*>(const_cast<float*>(out) + (c * NPIX + pid) * 4) = v;
        }
    }
}

} // namespace

extern "C" void kernel_launch(void* const* d_in, const int* in_sizes, int n_in,
                              void* d_out, int out_size, void* d_ws, size_t ws_size,
                              hipStream_t stream)
{
    const float* noisy = (const float*)d_in[0];
    const float* guid  = (const float*)d_in[1];
    const float* est   = (const float*)d_in[2];
    const float* var   = (const float*)d_in[3];
    float* out = (float*)d_out;

    statden<<<NPIX / PX, NTHR, 0, stream>>>(noisy, guid, est, var, out);
}